// Round 5
// baseline (35177.374 us; speedup 1.0000x reference)
//
#include <hip/hip_runtime.h>
#include <stdint.h>

// Problem constants (B,S,I,H,O) = (64, 2048, 256, 512, 256), all fp32.
#define Bn 64
#define Sn 2048
#define In 256
#define Hn 512
#define On 256

// ---------------------------------------------------------------------------
// BIT-EXACT-REPLICATION round. The dynamics are chaotic (per-step error gain
// ~3.2x, verified by four independent implementations all decorrelating to
// absmax ~100 while being deterministic). Passing requires reproducing the
// reference's arithmetic bit-for-bit, not just "correct fp32 math".
//
// XLA's f32 arithmetic, replicated here:
//  * tanh: XLA's Eigen-derived rational approximation (identical on XLA:CPU
//    and XLA:GPU): clamp to +/-7.99881172180175781, |x|<4e-4 passthrough,
//    odd degree-13 numerator / even degree-6 denominator, Horner with fma.
//  * GEMMs (Tensile/Eigen): each output element = ONE fma chain over the
//    contraction index in ascending order, single accumulator, alpha=1.
//  * Associations: xw = chain_i(x*Wxh) + bias_h   (einsum then +bias)
//                  u  = xw + chain_k(h*Whh)       (xw_t + h@Whh)
//                  y  = chain_k(h*Why) + bias_y
// Explicit fmaf() everywhere; no reassociation (hipcc default keeps order).
// ---------------------------------------------------------------------------
__device__ __forceinline__ float xla_tanh(float x) {
    const float ax = __builtin_fabsf(x);
    float xc = fmaxf(-7.99881172180175781f, fminf(7.99881172180175781f, x));
    const float x2 = xc * xc;
    float p = fmaf(x2, -2.76076847742355e-16f, 2.00018790482477e-13f);
    p = fmaf(x2, p, -8.60467152213735e-11f);
    p = fmaf(x2, p, 5.12229709037114e-08f);
    p = fmaf(x2, p, 1.48572235717979e-05f);
    p = fmaf(x2, p, 6.37261928875436e-04f);
    p = fmaf(x2, p, 4.89352455891786e-03f);
    p = xc * p;
    float q = fmaf(x2, 1.19825839466702e-06f, 1.18534705686654e-04f);
    q = fmaf(x2, q, 2.26843463243900e-03f);
    q = fmaf(x2, q, 4.89352518554385e-03f);
    return ax < 0.0004f ? x : p / q;
}

// ---------------------------------------------------------------------------
// Scan: one block per batch row (rows are independent!). 512 threads = one
// per h column j. h lives in LDS; x rows double-buffered in LDS; weights
// streamed from L2 (Whh+Wxh = 1.5 MB, shared by all 8 blocks of an XCD).
// Per step, thread j computes, in the reference's exact order:
//   xacc = fma-chain over i=0..255 of xs[i]*Wxh[i][j]    (ascending)
//   xw   = xacc + bias_h[j]
//   hacc = fma-chain over k=0..511 of hs[k]*Whh[k][j]    (ascending)
//   u    = xw + hacc ;  h_new[j] = xla_tanh(u)
// ---------------------------------------------------------------------------
__global__ __launch_bounds__(512) void rnn_scan(const float* __restrict__ x,
                                                const float* __restrict__ Wxh,
                                                const float* __restrict__ Whh,
                                                const float* __restrict__ bias_h,
                                                float* __restrict__ hlast) {
    const int b = blockIdx.x;
    const int j = threadIdx.x;

    __shared__ float hs[Hn];
    __shared__ float xs[2][In];

    hs[j] = 0.0f;
    if (j < In) xs[0][j] = x[(size_t)b * Sn * In + j];
    __syncthreads();

    const float bh = bias_h[j];
    const float* __restrict__ wx = Wxh + j;
    const float* __restrict__ wh = Whh + j;

    for (int t = 0; t < Sn; ++t) {
        const int p = t & 1;
        // prefetch next x row into the other LDS buffer (safe: its previous
        // readers finished before the barrier that ended step t-1)
        if (j < In && t + 1 < Sn)
            xs[1 - p][j] = x[((size_t)b * Sn + t + 1) * In + j];

        // einsum chain (ascending i, single accumulator, fma)
        float xacc = 0.0f;
#pragma unroll 8
        for (int i = 0; i < In; ++i)
            xacc = fmaf(xs[p][i], wx[(size_t)i * Hn], xacc);
        const float xw = xacc + bh;

        // h @ Whh chain (ascending k, single accumulator, fma)
        float hacc = 0.0f;
#pragma unroll 8
        for (int k = 0; k < Hn; ++k)
            hacc = fmaf(hs[k], wh[(size_t)k * Hn], hacc);

        const float u = xw + hacc;
        const float hnew = xla_tanh(u);

        __syncthreads();   // all reads of hs for step t complete
        hs[j] = hnew;
        __syncthreads();   // hs (and xs prefetch) ready for step t+1
    }

    hlast[(size_t)b * Hn + j] = hs[j];
}

// ---------------------------------------------------------------------------
// y[b][o] = fma-chain_k(h_last[b][k]*Why[k][o]) + bias_y[o]
// ---------------------------------------------------------------------------
__global__ __launch_bounds__(256) void out_gemm(const float* __restrict__ hlast,
                                                const float* __restrict__ Why,
                                                const float* __restrict__ bias_y,
                                                float* __restrict__ y) {
    const int b = blockIdx.x, o = threadIdx.x;
    __shared__ float hs[Hn];
    hs[o] = hlast[(size_t)b * Hn + o];
    hs[o + 256] = hlast[(size_t)b * Hn + o + 256];
    __syncthreads();
    float acc = 0.0f;
#pragma unroll 8
    for (int k = 0; k < Hn; ++k)
        acc = fmaf(hs[k], Why[(size_t)k * On + o], acc);
    y[(size_t)b * On + o] = acc + bias_y[o];
}

// ---------------------------------------------------------------------------
extern "C" void kernel_launch(void* const* d_in, const int* in_sizes, int n_in,
                              void* d_out, int out_size, void* d_ws, size_t ws_size,
                              hipStream_t stream) {
    // Map inputs by size (safety net; documented order is x,Wxh,Whh,Why,bh,by).
    // Sizes: x=33554432, Wxh=131072, Whh=262144, Why=131072, bias_h=512,
    // bias_y=256. The two 131072s keep their relative order (Wxh first).
    const float *x = nullptr, *Wxh = nullptr, *Whh = nullptr, *Why = nullptr,
                *bias_h = nullptr, *bias_y = nullptr;
    for (int i = 0; i < n_in; ++i) {
        const float* p = (const float*)d_in[i];
        const int sz = in_sizes[i];
        if (sz == Bn * Sn * In) x = p;
        else if (sz == Hn * Hn) Whh = p;
        else if (sz == In * Hn) { if (!Wxh) Wxh = p; else Why = p; }
        else if (sz == Hn) bias_h = p;
        else if (sz == On) bias_y = p;
    }
    float* y = (float*)d_out;
    float* hlast = (float*)d_ws;   // 64*512*4 = 131072 B, fully written by scan

    rnn_scan<<<dim3(Bn), dim3(Hn), 0, stream>>>(x, Wxh, Whh, bias_h, hlast);
    out_gemm<<<dim3(Bn), dim3(On), 0, stream>>>(hlast, Why, bias_y, y);
}

// Round 6
// 33436.255 us; speedup vs baseline: 1.0521x; 1.0521x over previous
//
#include <hip/hip_runtime.h>
#include <stdint.h>

// Problem constants (B,S,I,H,O) = (64, 2048, 256, 512, 256), all fp32.
#define Bn 64
#define Sn 2048
#define In 256
#define Hn 512
#define On 256
#define KS 384   // front-chain length (thread A); back = Hn - KS = 128 (thread B)

// ---------------------------------------------------------------------------
// BIT-EXACT constraint (proven R5, absmax 0.0): per output element the
// arithmetic must be exactly
//   xacc = fma-chain_{i=0..255 asc}(xs[i], Wxh[i][j]);  xw = xacc + bias_h[j]
//   hacc = fma-chain_{k=0..511 asc}(hs[k], Whh[k][j]);  u  = xw + hacc
//   h' = xla_tanh(u);   y = fma-chain_k(h[k],Why[k][o]) + bias_y[o]
// This round keeps those sequences bit-identical but moves ALL weight
// operands into VGPRs (R5 streamed them from L2 every step -> 17 us/step).
// A 768-reg column doesn't fit one thread (pool 512/SIMD), so the hacc chain
// is computed as prefix(A)+suffix(B) with an LDS handoff of the accumulator —
// same fma sequence, same bits.
// Partition: 256 blocks = 64 batches x 4 column-slices (128 cols). Block =
// 256 threads: tid<128 = "A" (384 Whh regs, chain k<384), tid>=128 = "B"
// (256 Wxh + 128 Whh regs, xacc + chain k>=384 + tanh + publish).
// ~420 VGPR -> 1 wave/SIMD -> 1 block/CU -> all 256 blocks co-resident
// (empirically proven by R2/R3 with this exact shape).
// Cross-block h exchange per step: deterministic flag/publish protocol
// (R2-proven): publish own 128 h to hpub slot (t+1)&1, s_barrier (drains
// vmcnt) -> tid0 release flag=t+1 -> consumers acquire-spin flag>=t and
// copy remote slices into LDS before their chains. Ascending-k consumption
// means remote latency overlaps the front chain's local prefix.
// ---------------------------------------------------------------------------
__device__ __forceinline__ float xla_tanh(float x) {
    const float ax = __builtin_fabsf(x);
    float xc = fmaxf(-7.99881172180175781f, fminf(7.99881172180175781f, x));
    const float x2 = xc * xc;
    float p = fmaf(x2, -2.76076847742355e-16f, 2.00018790482477e-13f);
    p = fmaf(x2, p, -8.60467152213735e-11f);
    p = fmaf(x2, p, 5.12229709037114e-08f);
    p = fmaf(x2, p, 1.48572235717979e-05f);
    p = fmaf(x2, p, 6.37261928875436e-04f);
    p = fmaf(x2, p, 4.89352455891786e-03f);
    p = xc * p;
    float q = fmaf(x2, 1.19825839466702e-06f, 1.18534705686654e-04f);
    q = fmaf(x2, q, 2.26843463243900e-03f);
    q = fmaf(x2, q, 4.89352518554385e-03f);
    return ax < 0.0004f ? x : p / q;
}

__global__ __launch_bounds__(256, 1) void rnn_scan(const float* __restrict__ x,
                                                   const float* __restrict__ Wxh,
                                                   const float* __restrict__ Whh,
                                                   const float* __restrict__ bias_h,
                                                   float* __restrict__ hpub,
                                                   int* __restrict__ flags,
                                                   float* __restrict__ hlast) {
    const int blk = blockIdx.x;
    const int b = blk & 63;          // batch
    const int s = blk >> 6;          // column-slice 0..3 (siblings = b mod 8 -> same XCD heuristic)
    const int tid = threadIdx.x;
    const int c = tid & 127;         // column within slice
    const bool isA = tid < 128;      // wave-uniform role split
    const int j = s * 128 + c;       // global column

    __shared__ float hs[2][Hn];      // double-buffered h (read t&1, write 1-(t&1))
    __shared__ float xs[2][In];      // double-buffered x row
    __shared__ float pacc[128];      // A->B chain-accumulator handoff

    // Weight registers (384 floats/thread, coalesced loads: lanes = consecutive j)
    float W0[KS];
    if (isA) {
#pragma unroll
        for (int k = 0; k < KS; ++k) W0[k] = Whh[(size_t)k * Hn + j];
    } else {
#pragma unroll
        for (int i = 0; i < In; ++i) W0[i] = Wxh[(size_t)i * Hn + j];
#pragma unroll
        for (int k = 0; k < 128; ++k) W0[In + k] = Whh[(size_t)(KS + k) * Hn + j];
    }
    const float bh = isA ? 0.f : bias_h[j];

    hs[0][tid] = 0.f;                          // h_0 = 0
    hs[0][tid + 256] = 0.f;
    xs[0][tid] = x[(size_t)b * Sn * In + tid]; // row 0 (256 threads = full row)
    __syncthreads();

    float* mypub = hpub + (size_t)(b * 4 + s) * 256;   // [slot][128]
    int* myflag = flags + (b * 4 + s) * 16;            // 64B-strided

    float hn = 0.f;

    for (int t = 0; t < Sn; ++t) {
        const int rp = t & 1;

        // ---- stage remote h_t slices into hs[rp] (t>=1; t=0 is all zeros) ----
        if (t > 0) {
            if (isA) {
                // A's chain covers k in [0,384) -> slices {0,1,2} minus own
#pragma unroll
                for (int r = 0; r < 3; ++r) {
                    if (r != s) {
                        const int* fl = flags + (b * 4 + r) * 16;
                        while (__hip_atomic_load(fl, __ATOMIC_ACQUIRE,
                                                 __HIP_MEMORY_SCOPE_AGENT) < t)
                            __builtin_amdgcn_s_sleep(1);
                        float v = __hip_atomic_load(
                            &hpub[(size_t)(b * 4 + r) * 256 + rp * 128 + c],
                            __ATOMIC_RELAXED, __HIP_MEMORY_SCOPE_AGENT);
                        hs[rp][r * 128 + c] = v;
                    }
                }
            } else if (s != 3) {
                // B's back chain covers k in [384,512) = slice 3
                const int* fl = flags + (b * 4 + 3) * 16;
                while (__hip_atomic_load(fl, __ATOMIC_ACQUIRE,
                                         __HIP_MEMORY_SCOPE_AGENT) < t)
                    __builtin_amdgcn_s_sleep(1);
                float v = __hip_atomic_load(
                    &hpub[(size_t)(b * 4 + 3) * 256 + rp * 128 + c],
                    __ATOMIC_RELAXED, __HIP_MEMORY_SCOPE_AGENT);
                hs[rp][384 + c] = v;
            }
        }
        __syncthreads();   // #0: hs[rp] complete (remote staged, local from t-1)

        float xw_ = 0.f;
        if (isA) {
            // hacc prefix: k = 0..383, ascending, single accumulator (exact R5 order)
            float acc = 0.f;
            const float4* h4 = (const float4*)&hs[rp][0];
#pragma unroll
            for (int q = 0; q < KS / 4; ++q) {
                float4 hv = h4[q];   // broadcast ds_read_b128
                acc = fmaf(hv.x, W0[4 * q + 0], acc);
                acc = fmaf(hv.y, W0[4 * q + 1], acc);
                acc = fmaf(hv.z, W0[4 * q + 2], acc);
                acc = fmaf(hv.w, W0[4 * q + 3], acc);
            }
            pacc[c] = acc;
        } else {
            // prefetch next x row (2 elems/thread), issued before xacc to hide latency
            float xn0 = 0.f, xn1 = 0.f;
            if (t + 1 < Sn) {
                xn0 = x[((size_t)b * Sn + t + 1) * In + c];
                xn1 = x[((size_t)b * Sn + t + 1) * In + 128 + c];
            }
            // xacc: i = 0..255, ascending (exact R5 order)
            float xa = 0.f;
            const float4* x4 = (const float4*)&xs[rp][0];
#pragma unroll
            for (int q = 0; q < In / 4; ++q) {
                float4 xv = x4[q];
                xa = fmaf(xv.x, W0[4 * q + 0], xa);
                xa = fmaf(xv.y, W0[4 * q + 1], xa);
                xa = fmaf(xv.z, W0[4 * q + 2], xa);
                xa = fmaf(xv.w, W0[4 * q + 3], xa);
            }
            xw_ = xa + bh;
            if (t + 1 < Sn) {
                xs[1 - rp][c] = xn0;
                xs[1 - rp][128 + c] = xn1;
            }
        }
        __syncthreads();   // #1: pacc ready

        if (!isA) {
            // hacc suffix: k = 384..511, continuing the SAME chain
            float acc = pacc[c];
            const float4* h4 = (const float4*)&hs[rp][KS];
#pragma unroll
            for (int q = 0; q < 32; ++q) {
                float4 hv = h4[q];
                acc = fmaf(hv.x, W0[In + 4 * q + 0], acc);
                acc = fmaf(hv.y, W0[In + 4 * q + 1], acc);
                acc = fmaf(hv.z, W0[In + 4 * q + 2], acc);
                acc = fmaf(hv.w, W0[In + 4 * q + 3], acc);
            }
            const float u = xw_ + acc;        // exact R5 association
            hn = xla_tanh(u);
            hs[1 - rp][j] = hn;               // local slice for step t+1
            if (t + 1 < Sn)
                __hip_atomic_store(&mypub[(1 - rp) * 128 + c], hn,
                                   __ATOMIC_RELAXED, __HIP_MEMORY_SCOPE_AGENT);
        }
        __syncthreads();   // #2: publishes drained (s_barrier forces vmcnt(0))

        if (tid == 0 && t + 1 < Sn)
            __hip_atomic_store(myflag, t + 1, __ATOMIC_RELEASE,
                               __HIP_MEMORY_SCOPE_AGENT);
    }

    if (!isA) hlast[(size_t)b * Hn + j] = hn;
}

// ---------------------------------------------------------------------------
// y[b][o] = fma-chain_k(h_last[b][k]*Why[k][o]) + bias_y[o]  (unchanged, R5-exact)
// ---------------------------------------------------------------------------
__global__ __launch_bounds__(256) void out_gemm(const float* __restrict__ hlast,
                                                const float* __restrict__ Why,
                                                const float* __restrict__ bias_y,
                                                float* __restrict__ y) {
    const int b = blockIdx.x, o = threadIdx.x;
    __shared__ float hs[Hn];
    hs[o] = hlast[(size_t)b * Hn + o];
    hs[o + 256] = hlast[(size_t)b * Hn + o + 256];
    __syncthreads();
    float acc = 0.0f;
#pragma unroll 8
    for (int k = 0; k < Hn; ++k)
        acc = fmaf(hs[k], Why[(size_t)k * On + o], acc);
    y[(size_t)b * On + o] = acc + bias_y[o];
}

// ---------------------------------------------------------------------------
extern "C" void kernel_launch(void* const* d_in, const int* in_sizes, int n_in,
                              void* d_out, int out_size, void* d_ws, size_t ws_size,
                              hipStream_t stream) {
    // Map inputs by size (x=33554432, Whh=262144, Wxh/Why=131072 in order,
    // bias_h=512, bias_y=256).
    const float *x = nullptr, *Wxh = nullptr, *Whh = nullptr, *Why = nullptr,
                *bias_h = nullptr, *bias_y = nullptr;
    for (int i = 0; i < n_in; ++i) {
        const float* p = (const float*)d_in[i];
        const int sz = in_sizes[i];
        if (sz == Bn * Sn * In) x = p;
        else if (sz == Hn * Hn) Whh = p;
        else if (sz == In * Hn) { if (!Wxh) Wxh = p; else Why = p; }
        else if (sz == Hn) bias_h = p;
        else if (sz == On) bias_y = p;
    }
    float* y = (float*)d_out;

    // workspace: hpub (64*4*2*128 floats = 256 KB) + flags (16 KB) + hlast (128 KB)
    char* ws = (char*)d_ws;
    float* hpub = (float*)ws;
    size_t hpub_bytes = (size_t)Bn * 4 * 2 * 128 * sizeof(float);
    int* flags = (int*)(ws + hpub_bytes);
    size_t flag_bytes = (size_t)Bn * 4 * 16 * sizeof(int);
    float* hlast = (float*)(ws + hpub_bytes + flag_bytes);

    // flags must start at 0 (ws re-poisoned to 0xAA each call); hpub needs no init
    hipMemsetAsync(flags, 0, flag_bytes, stream);

    rnn_scan<<<dim3(256), dim3(256), 0, stream>>>(x, Wxh, Whh, bias_h,
                                                  hpub, flags, hlast);
    out_gemm<<<dim3(Bn), dim3(On), 0, stream>>>(hlast, Why, bias_y, y);
}